// Round 5
// baseline (401.570 us; speedup 1.0000x reference)
//
#include <hip/hip_runtime.h>
#include <hip/hip_bf16.h>

typedef unsigned short ushort_t;
typedef __attribute__((ext_vector_type(8))) short s8;    // 8 bf16 (4 VGPRs)
typedef __attribute__((ext_vector_type(4))) float f4;    // MFMA C/D frag

__device__ __forceinline__ unsigned short f2bf(float f) {
  union { float f; unsigned int u; } c; c.f = f;
  unsigned int r = (c.u + 0x7fffu + ((c.u >> 16) & 1u)) >> 16;
  return (unsigned short)r;
}
__device__ __forceinline__ float bf2f(ushort_t u) {
  union { unsigned int i; float f; } c; c.i = ((unsigned int)u) << 16; return c.f;
}
__device__ __forceinline__ uint4 pack8(float4 a, float4 b) {
  uint4 r;
  r.x = (unsigned)f2bf(a.x) | ((unsigned)f2bf(a.y) << 16);
  r.y = (unsigned)f2bf(a.z) | ((unsigned)f2bf(a.w) << 16);
  r.z = (unsigned)f2bf(b.x) | ((unsigned)f2bf(b.y) << 16);
  r.w = (unsigned)f2bf(b.z) | ((unsigned)f2bf(b.w) << 16);
  return r;
}

// ---------- all weight transposes in one launch: dst[n][k] = bf16(src[k][n]) ----------
__global__ __launch_bounds__(256) void k_wt_all(
    const float* __restrict__ enc_w, const float* __restrict__ wq,
    const float* __restrict__ wk, const float* __restrict__ wv,
    const float* __restrict__ bn_w,
    ushort_t* __restrict__ enc_wT, ushort_t* __restrict__ wqkvT,
    ushort_t* __restrict__ bn_wT) {
  const int y = blockIdx.y;
  const int i = blockIdx.x * 256 + threadIdx.x;
  if (y == 0) {
    if (i < 131072) { const int n = i >> 9, k = i & 511; enc_wT[i] = f2bf(enc_w[k * 256 + n]); }
  } else if (y <= 3) {
    if (i < 65536) {
      const int n = i >> 8, k = i & 255;
      const float* src = (y == 1) ? wq : (y == 2) ? wk : wv;
      wqkvT[(y - 1) * 65536 + i] = f2bf(src[k * 256 + n]);
    }
  } else {
    if (i < 32768) { const int n = i >> 8, k = i & 255; bn_wT[i] = f2bf(bn_w[k * 128 + n]); }
  }
}

// ------- encoder GEMM + LN + ReLU; A = lf fp32 converted in staging -------
// NN=256, KK=512; grid 256 blocks, 4 waves; wave tile 32 x 128
__global__ __launch_bounds__(256, 2) void k_gemm_enc(
    const float* __restrict__ A, const ushort_t* __restrict__ WT,
    const float* __restrict__ bia, const float* __restrict__ g,
    const float* __restrict__ beta, ushort_t* __restrict__ out) {
  __shared__ short Al[64 * 72];
  __shared__ short Bl[256 * 72];
  __shared__ float red1[64][2], red2[64][2];
  const int t = threadIdx.x;
  const int wv = t >> 6, lane = t & 63, l16 = lane & 15, quad = lane >> 4;
  const int wm = wv >> 1, wn = wv & 1;
  const int row0 = blockIdx.x * 64;

  f4 acc[2][8];
#pragma unroll
  for (int mf = 0; mf < 2; ++mf)
#pragma unroll
    for (int nf = 0; nf < 8; ++nf) acc[mf][nf] = (f4){0.f, 0.f, 0.f, 0.f};

  for (int k0 = 0; k0 < 512; k0 += 64) {
    __syncthreads();
#pragma unroll
    for (int i = 0; i < 2; ++i) {       // stage A: fp32 -> bf16
      const int ch = t + i * 256;
      const int r = ch >> 3, c8 = ch & 7;
      const float* src = &A[(size_t)(row0 + r) * 512 + k0 + c8 * 8];
      *(uint4*)&Al[r * 72 + c8 * 8] =
          pack8(*(const float4*)src, *(const float4*)(src + 4));
    }
#pragma unroll
    for (int i = 0; i < 8; ++i) {       // stage B: 256 x 64
      const int ch = t + i * 256;
      const int r = ch >> 3, c8 = ch & 7;
      *(uint4*)&Bl[r * 72 + c8 * 8] =
          *(const uint4*)&WT[(size_t)r * 512 + k0 + c8 * 8];
    }
    __syncthreads();
#pragma unroll
    for (int kc = 0; kc < 2; ++kc) {
      s8 af[2];
      af[0] = *(const s8*)&Al[(wm * 32 + l16) * 72 + kc * 32 + quad * 8];
      af[1] = *(const s8*)&Al[(wm * 32 + 16 + l16) * 72 + kc * 32 + quad * 8];
#pragma unroll
      for (int nf = 0; nf < 8; ++nf) {
        const s8 bf = *(const s8*)&Bl[(wn * 128 + nf * 16 + l16) * 72 + kc * 32 + quad * 8];
        acc[0][nf] = __builtin_amdgcn_mfma_f32_16x16x32_bf16(af[0], bf, acc[0][nf], 0, 0, 0);
        acc[1][nf] = __builtin_amdgcn_mfma_f32_16x16x32_bf16(af[1], bf, acc[1][nf], 0, 0, 0);
      }
    }
  }
  float bi[8], gg[8], bb[8];
#pragma unroll
  for (int nf = 0; nf < 8; ++nf) {
    const int col = wn * 128 + nf * 16 + l16;
    bi[nf] = bia[col]; gg[nf] = g[col]; bb[nf] = beta[col];
  }
  float s1[2][4], s2[2][4];
#pragma unroll
  for (int mf = 0; mf < 2; ++mf)
#pragma unroll
    for (int r = 0; r < 4; ++r) { s1[mf][r] = 0.f; s2[mf][r] = 0.f; }
#pragma unroll
  for (int mf = 0; mf < 2; ++mf)
#pragma unroll
    for (int nf = 0; nf < 8; ++nf)
#pragma unroll
      for (int r = 0; r < 4; ++r) {
        const float v = acc[mf][nf][r] + bi[nf];
        acc[mf][nf][r] = v;
        s1[mf][r] += v; s2[mf][r] += v * v;
      }
#pragma unroll
  for (int m = 1; m < 16; m <<= 1) {
#pragma unroll
    for (int mf = 0; mf < 2; ++mf)
#pragma unroll
      for (int r = 0; r < 4; ++r) {
        s1[mf][r] += __shfl_xor(s1[mf][r], m);
        s2[mf][r] += __shfl_xor(s2[mf][r], m);
      }
  }
  if (l16 == 0) {
#pragma unroll
    for (int mf = 0; mf < 2; ++mf)
#pragma unroll
      for (int r = 0; r < 4; ++r) {
        const int rl = wm * 32 + mf * 16 + quad * 4 + r;
        red1[rl][wn] = s1[mf][r]; red2[rl][wn] = s2[mf][r];
      }
  }
  __syncthreads();
#pragma unroll
  for (int mf = 0; mf < 2; ++mf)
#pragma unroll
    for (int r = 0; r < 4; ++r) {
      const int rl = wm * 32 + mf * 16 + quad * 4 + r;
      const float mu = (red1[rl][0] + red1[rl][1]) * (1.f / 256.f);
      const float var = (red2[rl][0] + red2[rl][1]) * (1.f / 256.f) - mu * mu;
      const float rstd = rsqrtf(var + 1e-5f);
#pragma unroll
      for (int nf = 0; nf < 8; ++nf) {
        const int col = wn * 128 + nf * 16 + l16;
        const float v = (acc[mf][nf][r] - mu) * rstd * gg[nf] + bb[nf];
        out[(size_t)(row0 + rl) * 256 + col] = f2bf(fmaxf(v, 0.f));
      }
    }
}

// ---- QKV GEMM: A=h_bf, WT=wqkvT [768][256]; q scaled 1/16, v -> VT ----
__global__ __launch_bounds__(256, 4) void k_gemm_qkv(
    const ushort_t* __restrict__ A, const ushort_t* __restrict__ WT,
    const float* __restrict__ bq, const float* __restrict__ bk,
    const float* __restrict__ bv,
    ushort_t* __restrict__ q, ushort_t* __restrict__ k, ushort_t* __restrict__ vt) {
  __shared__ short Al[64 * 72];
  __shared__ short Bl[128 * 72];
  const int t = threadIdx.x;
  const int wv = t >> 6, lane = t & 63, l16 = lane & 15, quad = lane >> 4;
  const int wm = wv >> 1, wn = wv & 1;
  const int row0 = blockIdx.x * 64;
  const int nb = blockIdx.y;
  const int type = nb >> 1;
  const ushort_t* wtb = WT + (size_t)nb * 128 * 256;

  f4 acc[2][4];
#pragma unroll
  for (int mf = 0; mf < 2; ++mf)
#pragma unroll
    for (int nf = 0; nf < 4; ++nf) acc[mf][nf] = (f4){0.f, 0.f, 0.f, 0.f};

  for (int k0 = 0; k0 < 256; k0 += 64) {
    __syncthreads();
#pragma unroll
    for (int i = 0; i < 2; ++i) {
      const int ch = t + i * 256;
      const int r = ch >> 3, c8 = ch & 7;
      *(uint4*)&Al[r * 72 + c8 * 8] =
          *(const uint4*)&A[(size_t)(row0 + r) * 256 + k0 + c8 * 8];
    }
#pragma unroll
    for (int i = 0; i < 4; ++i) {
      const int ch = t + i * 256;
      const int r = ch >> 3, c8 = ch & 7;
      *(uint4*)&Bl[r * 72 + c8 * 8] =
          *(const uint4*)&wtb[(size_t)r * 256 + k0 + c8 * 8];
    }
    __syncthreads();
#pragma unroll
    for (int kc = 0; kc < 2; ++kc) {
      s8 af[2];
      af[0] = *(const s8*)&Al[(wm * 32 + l16) * 72 + kc * 32 + quad * 8];
      af[1] = *(const s8*)&Al[(wm * 32 + 16 + l16) * 72 + kc * 32 + quad * 8];
#pragma unroll
      for (int nf = 0; nf < 4; ++nf) {
        const s8 bf = *(const s8*)&Bl[(wn * 64 + nf * 16 + l16) * 72 + kc * 32 + quad * 8];
        acc[0][nf] = __builtin_amdgcn_mfma_f32_16x16x32_bf16(af[0], bf, acc[0][nf], 0, 0, 0);
        acc[1][nf] = __builtin_amdgcn_mfma_f32_16x16x32_bf16(af[1], bf, acc[1][nf], 0, 0, 0);
      }
    }
  }
  const float* bias = (type == 0) ? bq : (type == 1) ? bk : bv;
#pragma unroll
  for (int nf = 0; nf < 4; ++nf) {
    const int colg = nb * 128 + wn * 64 + nf * 16 + l16;
    const int col = colg - type * 256;
    const float bi = bias[col];
    if (type == 2) {
      const int b = row0 >> 11;
#pragma unroll
      for (int mf = 0; mf < 2; ++mf) {
        const int n = (row0 & 2047) + wm * 32 + mf * 16 + quad * 4;
        ushort4 pk;
        pk.x = f2bf(acc[mf][nf][0] + bi);
        pk.y = f2bf(acc[mf][nf][1] + bi);
        pk.z = f2bf(acc[mf][nf][2] + bi);
        pk.w = f2bf(acc[mf][nf][3] + bi);
        *(ushort4*)&vt[((size_t)b * 256 + col) * 2048 + n] = pk;
      }
    } else {
      ushort_t* dst = (type == 0) ? q : k;
      const float sc = (type == 0) ? 0.0625f : 1.f;
#pragma unroll
      for (int mf = 0; mf < 2; ++mf)
#pragma unroll
        for (int r = 0; r < 4; ++r) {
          const int row = row0 + wm * 32 + mf * 16 + quad * 4 + r;
          dst[(size_t)row * 256 + col] = f2bf((acc[mf][nf][r] + bi) * sc);
        }
    }
  }
}

// ---- MFMA flash attention v2: ks=3 key split, reg-prefetch K, direct-global V ----
// grid (32 qtiles, 3 ks, 8 batch), 256 thr = 4 waves x 16 q; LDS 43 KB -> 3 blocks/CU
#define KLS 264
#define PLS 72
__global__ __launch_bounds__(256, 3) void k_attn(
    const ushort_t* __restrict__ qb, const ushort_t* __restrict__ kb,
    const ushort_t* __restrict__ vtb,
    const float* __restrict__ coords, const int* __restrict__ mask,
    const float* __restrict__ gam,
    float* __restrict__ Op, float* __restrict__ mws, float* __restrict__ lws) {
  __shared__ short klds[64 * KLS];   // 33792 B
  __shared__ short pl[64 * PLS];     //  9216 B
  const int t = threadIdx.x;
  const int wv = t >> 6, lane = t & 63, l16 = lane & 15, quad = lane >> 4;
  const int b = blockIdx.z, ks = blockIdx.y;
  const int qw = blockIdx.x * 64 + wv * 16;
  const int kt0 = ks * 11;
  const int ktn = (ks < 2) ? 11 : 10;   // keys: 704 + 704 + 640 = 2048

  float rcx[4], rcy[4];
#pragma unroll
  for (int r = 0; r < 4; ++r) {
    const float2 cc = ((const float2*)coords)[b * 2048 + qw + quad * 4 + r];
    rcx[r] = cc.x; rcy[r] = cc.y;
  }
  const float gamma = fabsf(gam[0]);

  f4 o[16];
#pragma unroll
  for (int i = 0; i < 16; ++i) o[i] = (f4){0.f, 0.f, 0.f, 0.f};
  float mrun[4] = {-1e30f, -1e30f, -1e30f, -1e30f};
  float lrun[4] = {0.f, 0.f, 0.f, 0.f};

  const ushort_t* kbb = kb + (size_t)b * 2048 * 256;
  const ushort_t* qrow = qb + ((size_t)b * 2048 + qw + l16) * 256 + quad * 8;
  const ushort_t* vbase0 = vtb + ((size_t)b * 256 + l16) * 2048 + quad * 8;

  // prefetch first K tile into registers
  uint4 kpre[8];
#pragma unroll
  for (int i = 0; i < 8; ++i) {
    const int ch = t + i * 256;
    const int r = ch >> 5, c = ch & 31;
    kpre[i] = *(const uint4*)(kbb + (size_t)(kt0 * 64 + r) * 256 + c * 8);
  }

  for (int kt = kt0; kt < kt0 + ktn; ++kt) {
    const int m0 = kt * 64;
    __syncthreads();                    // prev tile's klds reads done
#pragma unroll
    for (int i = 0; i < 8; ++i) {       // commit prefetched K to LDS
      const int ch = t + i * 256;
      const int r = ch >> 5, c = ch & 31;
      *(uint4*)&klds[r * KLS + c * 8] = kpre[i];
    }
    const int ktp = (kt + 1 < kt0 + ktn) ? kt + 1 : kt;   // clamp (last iter harmless)
#pragma unroll
    for (int i = 0; i < 8; ++i) {       // issue next-tile loads (reg dest: not drained by barrier)
      const int ch = t + i * 256;
      const int r = ch >> 5, c = ch & 31;
      kpre[i] = *(const uint4*)(kbb + (size_t)(ktp * 64 + r) * 256 + c * 8);
    }
    __syncthreads();                    // klds ready
    // Q A-frags (L1-resident), QK^T
    s8 qa[8];
#pragma unroll
    for (int c = 0; c < 8; ++c) qa[c] = *(const s8*)(qrow + c * 32);
    f4 sc[4];
#pragma unroll
    for (int s = 0; s < 4; ++s) sc[s] = (f4){0.f, 0.f, 0.f, 0.f};
#pragma unroll
    for (int s = 0; s < 4; ++s) {
      const short* kr = &klds[(s * 16 + l16) * KLS + quad * 8];
#pragma unroll
      for (int c = 0; c < 8; ++c) {
        const s8 bf = *(const s8*)(kr + c * 32);
        sc[s] = __builtin_amdgcn_mfma_f32_16x16x32_bf16(qa[c], bf, sc[s], 0, 0, 0);
      }
    }
    // online softmax on raw scores
    float mt[4];
#pragma unroll
    for (int r = 0; r < 4; ++r)
      mt[r] = fmaxf(fmaxf(sc[0][r], sc[1][r]), fmaxf(sc[2][r], sc[3][r]));
#pragma unroll
    for (int o2 = 1; o2 < 16; o2 <<= 1) {
#pragma unroll
      for (int r = 0; r < 4; ++r) mt[r] = fmaxf(mt[r], __shfl_xor(mt[r], o2));
    }
    float alpha[4];
#pragma unroll
    for (int r = 0; r < 4; ++r) {
      const float mn = fmaxf(mrun[r], mt[r]);
      alpha[r] = __expf(mrun[r] - mn);
      mrun[r] = mn;
    }
    float p[4][4], ls[4] = {0.f, 0.f, 0.f, 0.f};
#pragma unroll
    for (int s = 0; s < 4; ++s) {
#pragma unroll
      for (int r = 0; r < 4; ++r) { p[s][r] = __expf(sc[s][r] - mrun[r]); ls[r] += p[s][r]; }
    }
#pragma unroll
    for (int o2 = 1; o2 < 16; o2 <<= 1) {
#pragma unroll
      for (int r = 0; r < 4; ++r) ls[r] += __shfl_xor(ls[r], o2);
    }
#pragma unroll
    for (int r = 0; r < 4; ++r) lrun[r] = lrun[r] * alpha[r] + ls[r];
    // weights = p * exp(-gamma*dist) * maskf -> per-wave pl band
#pragma unroll
    for (int s = 0; s < 4; ++s) {
      const int m = m0 + s * 16 + l16;
      const float2 cc = ((const float2*)coords)[b * 2048 + m];
      const float mf = mask[b * 2048 + m] ? 0.f : 1.f;
#pragma unroll
      for (int r = 0; r < 4; ++r) {
        const float dx = rcx[r] - cc.x, dy = rcy[r] - cc.y;
        const float dist = sqrtf(fmaxf(dx * dx + dy * dy, 0.f));
        const float w = p[s][r] * __expf(-gamma * dist) * mf;
        pl[(wv * 16 + quad * 4 + r) * PLS + s * 16 + l16] = (short)f2bf(w);
      }
    }
#pragma unroll
    for (int i = 0; i < 16; ++i) {
#pragma unroll
      for (int r = 0; r < 4; ++r) o[i][r] *= alpha[r];
    }
    const s8 pa0 = *(const s8*)&pl[(wv * 16 + l16) * PLS + quad * 8];
    const s8 pa1 = *(const s8*)&pl[(wv * 16 + l16) * PLS + 32 + quad * 8];
    // PV: V B-frags direct from global VT (16B contiguous per lane)
    const ushort_t* vb = vbase0 + m0;
#pragma unroll
    for (int ds2 = 0; ds2 < 16; ++ds2) {
      const ushort_t* vr = vb + (size_t)ds2 * 16 * 2048;
      const s8 b0 = *(const s8*)vr;
      const s8 b1 = *(const s8*)(vr + 32);
      o[ds2] = __builtin_amdgcn_mfma_f32_16x16x32_bf16(pa0, b0, o[ds2], 0, 0, 0);
      o[ds2] = __builtin_amdgcn_mfma_f32_16x16x32_bf16(pa1, b1, o[ds2], 0, 0, 0);
    }
  }
  // write partial O and stats
  float* OpK = Op + (size_t)ks * 4194304;
#pragma unroll
  for (int r = 0; r < 4; ++r) {
    float* orow = OpK + ((size_t)b * 2048 + qw + quad * 4 + r) * 256 + l16;
#pragma unroll
    for (int ds2 = 0; ds2 < 16; ++ds2) orow[ds2 * 16] = o[ds2][r];
  }
  if (l16 == 0) {
#pragma unroll
    for (int r = 0; r < 4; ++r) {
      mws[ks * 16384 + b * 2048 + qw + quad * 4 + r] = mrun[r];
      lws[ks * 16384 + b * 2048 + qw + quad * 4 + r] = lrun[r];
    }
  }
}

// ---- BN GEMM + LN + ReLU with fused 3-way softmax merge in A-staging ----
// NN=128, KK=256; grid 256 blocks
__global__ __launch_bounds__(256, 2) void k_gemm_bn(
    const float* __restrict__ Op, const float* __restrict__ mws,
    const float* __restrict__ lws, const ushort_t* __restrict__ WT,
    const float* __restrict__ bia, const float* __restrict__ g,
    const float* __restrict__ beta, ushort_t* __restrict__ out) {
  __shared__ short Al[64 * 72];
  __shared__ short Bl[128 * 72];
  __shared__ float red1[64][2], red2[64][2];
  __shared__ float sC[64][3];
  const int t = threadIdx.x;
  const int wv = t >> 6, lane = t & 63, l16 = lane & 15, quad = lane >> 4;
  const int wm = wv >> 1, wn = wv & 1;
  const int row0 = blockIdx.x * 64;

  if (t < 64) {   // per-row merge coefficients
    const int row = row0 + t;
    const float m0 = mws[row], m1 = mws[16384 + row], m2 = mws[32768 + row];
    const float l0 = lws[row], l1 = lws[16384 + row], l2 = lws[32768 + row];
    const float M = fmaxf(fmaxf(m0, m1), m2);
    const float a0 = __expf(m0 - M), a1 = __expf(m1 - M), a2 = __expf(m2 - M);
    const float rd = 1.f / (l0 * a0 + l1 * a1 + l2 * a2);
    sC[t][0] = a0 * rd; sC[t][1] = a1 * rd; sC[t][2] = a2 * rd;
  }

  f4 acc[2][4];
#pragma unroll
  for (int mf = 0; mf < 2; ++mf)
#pragma unroll
    for (int nf = 0; nf < 4; ++nf) acc[mf][nf] = (f4){0.f, 0.f, 0.f, 0.f};

  for (int k0 = 0; k0 < 256; k0 += 64) {
    __syncthreads();
#pragma unroll
    for (int i = 0; i < 2; ++i) {   // stage A: merge 3 partials -> bf16
      const int ch = t + i * 256;
      const int r = ch >> 3, c8 = ch & 7;
      const float c0 = sC[r][0], c1 = sC[r][1], c2 = sC[r][2];
      const size_t off = (size_t)(row0 + r) * 256 + k0 + c8 * 8;
      const float4 xa0 = *(const float4*)&Op[off];
      const float4 xb0 = *(const float4*)&Op[off + 4];
      const float4 xa1 = *(const float4*)&Op[4194304 + off];
      const float4 xb1 = *(const float4*)&Op[4194304 + off + 4];
      const float4 xa2 = *(const float4*)&Op[8388608 + off];
      const float4 xb2 = *(const float4*)&Op[8388608 + off + 4];
      float4 ea, eb;
      ea.x = c0 * xa0.x + c1 * xa1.x + c2 * xa2.x;
      ea.y = c0 * xa0.y + c1 * xa1.y + c2 * xa2.y;
      ea.z = c0 * xa0.z + c1 * xa1.z + c2 * xa2.z;
      ea.w = c0 * xa0.w + c1 * xa1.w + c2 * xa2.w;
      eb.x = c0 * xb0.x + c1 * xb1.x + c2 * xb2.x;
      eb.y = c0 * xb0.y + c1 * xb1.y + c2 * xb2.y;
      eb.z = c0 * xb0.z + c1 * xb1.z + c2 * xb2.z;
      eb.w = c0 * xb0.w + c1 * xb1.w + c2 * xb2.w;
      *(uint4*)&Al[r * 72 + c8 * 8] = pack8(ea, eb);
    }
#pragma unroll
    for (int i = 0; i < 4; ++i) {
      const int ch = t + i * 256;
      const int r = ch >> 3, c8 = ch & 7;
      *(uint4*)&Bl[r * 72 + c8 * 8] =
          *(const uint4*)&WT[(size_t)r * 256 + k0 + c8 * 8];
    }
    __syncthreads();
#pragma unroll
    for (int kc = 0; kc < 2; ++kc) {
      s8 af[2];
      af[0] = *(const s8*)&Al[(wm * 32 + l16) * 72 + kc * 32 + quad * 8];
      af[1] = *(const s8*)&Al[(wm * 32 + 16 + l16) * 72 + kc * 32 + quad * 8];
#pragma unroll
      for (int nf = 0; nf < 4; ++nf) {
        const s8 bf = *(const s8*)&Bl[(wn * 64 + nf * 16 + l16) * 72 + kc * 32 + quad * 8];
        acc[0][nf] = __builtin_amdgcn_mfma_f32_16x16x32_bf16(af[0], bf, acc[0][nf], 0, 0, 0);
        acc[1][nf] = __builtin_amdgcn_mfma_f32_16x16x32_bf16(af[1], bf, acc[1][nf], 0, 0, 0);
      }
    }
  }
  float bi[4], gg[4], bb[4];
#pragma unroll
  for (int nf = 0; nf < 4; ++nf) {
    const int col = wn * 64 + nf * 16 + l16;
    bi[nf] = bia[col]; gg[nf] = g[col]; bb[nf] = beta[col];
  }
  float s1[2][4], s2[2][4];
#pragma unroll
  for (int mf = 0; mf < 2; ++mf)
#pragma unroll
    for (int r = 0; r < 4; ++r) { s1[mf][r] = 0.f; s2[mf][r] = 0.f; }
#pragma unroll
  for (int mf = 0; mf < 2; ++mf)
#pragma unroll
    for (int nf = 0; nf < 4; ++nf)
#pragma unroll
      for (int r = 0; r < 4; ++r) {
        const float v = acc[mf][nf][r] + bi[nf];
        acc[mf][nf][r] = v;
        s1[mf][r] += v; s2[mf][r] += v * v;
      }
#pragma unroll
  for (int m = 1; m < 16; m <<= 1) {
#pragma unroll
    for (int mf = 0; mf < 2; ++mf)
#pragma unroll
      for (int r = 0; r < 4; ++r) {
        s1[mf][r] += __shfl_xor(s1[mf][r], m);
        s2[mf][r] += __shfl_xor(s2[mf][r], m);
      }
  }
  if (l16 == 0) {
#pragma unroll
    for (int mf = 0; mf < 2; ++mf)
#pragma unroll
      for (int r = 0; r < 4; ++r) {
        const int rl = wm * 32 + mf * 16 + quad * 4 + r;
        red1[rl][wn] = s1[mf][r]; red2[rl][wn] = s2[mf][r];
      }
  }
  __syncthreads();
#pragma unroll
  for (int mf = 0; mf < 2; ++mf)
#pragma unroll
    for (int r = 0; r < 4; ++r) {
      const int rl = wm * 32 + mf * 16 + quad * 4 + r;
      const float mu = (red1[rl][0] + red1[rl][1]) * (1.f / 128.f);
      const float var = (red2[rl][0] + red2[rl][1]) * (1.f / 128.f) - mu * mu;
      const float rstd = rsqrtf(var + 1e-5f);
#pragma unroll
      for (int nf = 0; nf < 4; ++nf) {
        const int col = wn * 64 + nf * 16 + l16;
        const float v = (acc[mf][nf][r] - mu) * rstd * gg[nf] + bb[nf];
        out[(size_t)(row0 + rl) * 128 + col] = f2bf(fmaxf(v, 0.f));
      }
    }
}

// ---------------- masked mean pool, two-stage ----------------
__global__ __launch_bounds__(128) void k_pool1(
    const ushort_t* __restrict__ obn, const int* __restrict__ mask,
    float* __restrict__ pp) {
  const int g = blockIdx.x, b = blockIdx.y, d = threadIdx.x;
  const ushort_t* ob = obn + ((size_t)b * 2048 + g * 128) * 128;
  const int* mb = mask + b * 2048 + g * 128;
  float s = 0.f, cnt = 0.f;
  for (int n = 0; n < 128; ++n) {
    const float w = mb[n] ? 0.f : 1.f;
    s += w * bf2f(ob[(size_t)n * 128 + d]);
    cnt += w;
  }
  pp[(b * 16 + g) * 132 + d] = s;
  if (d == 0) pp[(b * 16 + g) * 132 + 128] = cnt;
}

__global__ __launch_bounds__(128) void k_pool2(
    const float* __restrict__ pp, float* __restrict__ pooled, float* __restrict__ dout) {
  const int b = blockIdx.x, d = threadIdx.x;
  float s = 0.f, cnt = 0.f;
  for (int g = 0; g < 16; ++g) {
    s += pp[(b * 16 + g) * 132 + d];
    cnt += pp[(b * 16 + g) * 132 + 128];
  }
  const float p = s / fmaxf(cnt, 1e-9f);
  pooled[b * 128 + d] = p;
  dout[80 + b * 128 + d] = p;
}

// ---------------- head ----------------
__global__ __launch_bounds__(64) void k_head(
    const float* __restrict__ pooled, const float* __restrict__ c1w, const float* __restrict__ c1b,
    const float* __restrict__ c2w, const float* __restrict__ c2b, float* __restrict__ dout) {
  __shared__ float ps[128];
  __shared__ float h1[64];
  const int b = blockIdx.x, t = threadIdx.x;
  ps[t] = pooled[b * 128 + t];
  ps[64 + t] = pooled[b * 128 + 64 + t];
  __syncthreads();
  float acc = c1b[t];
  for (int d = 0; d < 128; ++d) acc += ps[d] * c1w[d * 64 + t];
  h1[t] = fmaxf(acc, 0.f);
  __syncthreads();
  if (t < 10) {
    float a2 = c2b[t];
    for (int j = 0; j < 64; ++j) a2 += h1[j] * c2w[j * 10 + t];
    dout[b * 10 + t] = a2;
  }
}

extern "C" void kernel_launch(void* const* d_in, const int* in_sizes, int n_in,
                              void* d_out, int out_size, void* d_ws, size_t ws_size,
                              hipStream_t stream) {
  const float* lf     = (const float*)d_in[0];
  const float* coords = (const float*)d_in[1];
  const int*   mask   = (const int*)d_in[2];
  const float* enc_w  = (const float*)d_in[3];
  const float* enc_b  = (const float*)d_in[4];
  const float* enc_g  = (const float*)d_in[5];
  const float* enc_be = (const float*)d_in[6];
  const float* gamma  = (const float*)d_in[7];
  const float* wq     = (const float*)d_in[8];
  const float* bq     = (const float*)d_in[9];
  const float* wk     = (const float*)d_in[10];
  const float* bk     = (const float*)d_in[11];
  const float* wv     = (const float*)d_in[12];
  const float* bv     = (const float*)d_in[13];
  const float* bn_w   = (const float*)d_in[14];
  const float* bn_b   = (const float*)d_in[15];
  const float* bn_g   = (const float*)d_in[16];
  const float* bn_be  = (const float*)d_in[17];
  const float* c1w    = (const float*)d_in[18];
  const float* c1b    = (const float*)d_in[19];
  const float* c2w    = (const float*)d_in[20];
  const float* c2b    = (const float*)d_in[21];

  // ws layout (float units), ~81 MB (<=92 MB proven safe in R2):
  //  [0,2M)    h_bf (ushort)       [2M,4M)   q_bf      [4M,6M)  k_bf
  //  [6M,8M)   vt_bf               [8M,20M)  Op[3] fp32 partials
  //  obn_bf aliases Op0 ([8M,9M)) after attention
  //  [20M,...) enc_wT | wqkvT | bn_wT | mws | lws | ppart | pooled
  float* ws = (float*)d_ws;
  ushort_t* h_bf   = (ushort_t*)ws;
  ushort_t* q_bf   = (ushort_t*)(ws + 2097152);
  ushort_t* k_bf   = (ushort_t*)(ws + 4194304);
  ushort_t* vt_bf  = (ushort_t*)(ws + 6291456);
  float*    Op     = ws + 8388608;                 // 3 x 4194304 floats
  ushort_t* obn_bf = (ushort_t*)(ws + 8388608);    // aliases Op0 after k_attn
  ushort_t* enc_wT = (ushort_t*)(ws + 20971520);   // [256][512]
  ushort_t* wqkvT  = (ushort_t*)(ws + 21037056);   // [768][256]
  ushort_t* bn_wT  = (ushort_t*)(ws + 21135360);   // [128][256]
  float*    mws    = ws + 21151744;                // 3 x 16384
  float*    lws    = ws + 21200896;                // 3 x 16384
  float*    ppart  = ws + 21250048;                // 8*16*132
  float*    pooled = ws + 21266944;                // 1024
  float* out = (float*)d_out;

  k_wt_all<<<dim3(512, 5), 256, 0, stream>>>(enc_w, wq, wk, wv, bn_w,
                                             enc_wT, wqkvT, bn_wT);
  k_gemm_enc<<<256, 256, 0, stream>>>(lf, enc_wT, enc_b, enc_g, enc_be, h_bf);
  k_gemm_qkv<<<dim3(256, 6), 256, 0, stream>>>(h_bf, wqkvT, bq, bk, bv, q_bf, k_bf, vt_bf);
  k_attn<<<dim3(32, 3, 8), 256, 0, stream>>>(q_bf, k_bf, vt_bf, coords, mask, gamma,
                                             Op, mws, lws);
  k_gemm_bn<<<256, 256, 0, stream>>>(Op, mws, lws, bn_wT, bn_b, bn_g, bn_be, obn_bf);
  k_pool1<<<dim3(16, 8), 128, 0, stream>>>(obn_bf, mask, ppart);
  k_pool2<<<8, 128, 0, stream>>>(ppart, pooled, out);
  k_head<<<8, 64, 0, stream>>>(pooled, c1w, c1b, c2w, c2b, out);
}

// Round 6
// 362.947 us; speedup vs baseline: 1.1064x; 1.1064x over previous
//
#include <hip/hip_runtime.h>
#include <hip/hip_bf16.h>

typedef unsigned short ushort_t;
typedef __attribute__((ext_vector_type(8))) short s8;    // 8 bf16 (4 VGPRs)
typedef __attribute__((ext_vector_type(4))) float f4;    // MFMA C/D frag

__device__ __forceinline__ unsigned short f2bf(float f) {
  union { float f; unsigned int u; } c; c.f = f;
  unsigned int r = (c.u + 0x7fffu + ((c.u >> 16) & 1u)) >> 16;
  return (unsigned short)r;
}
__device__ __forceinline__ float bf2f(ushort_t u) {
  union { unsigned int i; float f; } c; c.i = ((unsigned int)u) << 16; return c.f;
}
__device__ __forceinline__ uint4 pack8(float4 a, float4 b) {
  uint4 r;
  r.x = (unsigned)f2bf(a.x) | ((unsigned)f2bf(a.y) << 16);
  r.y = (unsigned)f2bf(a.z) | ((unsigned)f2bf(a.w) << 16);
  r.z = (unsigned)f2bf(b.x) | ((unsigned)f2bf(b.y) << 16);
  r.w = (unsigned)f2bf(b.z) | ((unsigned)f2bf(b.w) << 16);
  return r;
}

// ---------- all weight transposes in one launch: dst[n][k] = bf16(src[k][n]) ----------
__global__ __launch_bounds__(256) void k_wt_all(
    const float* __restrict__ enc_w, const float* __restrict__ wq,
    const float* __restrict__ wk, const float* __restrict__ wv,
    const float* __restrict__ bn_w,
    ushort_t* __restrict__ enc_wT, ushort_t* __restrict__ wqkvT,
    ushort_t* __restrict__ bn_wT) {
  const int y = blockIdx.y;
  const int i = blockIdx.x * 256 + threadIdx.x;
  if (y == 0) {
    if (i < 131072) { const int n = i >> 9, k = i & 511; enc_wT[i] = f2bf(enc_w[k * 256 + n]); }
  } else if (y <= 3) {
    if (i < 65536) {
      const int n = i >> 8, k = i & 255;
      const float* src = (y == 1) ? wq : (y == 2) ? wk : wv;
      wqkvT[(y - 1) * 65536 + i] = f2bf(src[k * 256 + n]);
    }
  } else {
    if (i < 32768) { const int n = i >> 8, k = i & 255; bn_wT[i] = f2bf(bn_w[k * 128 + n]); }
  }
}

// ------- encoder GEMM + LN + ReLU; 32-row blocks (grid 512), A fp32->bf16 in staging -------
__global__ __launch_bounds__(256, 3) void k_gemm_enc(
    const float* __restrict__ A, const ushort_t* __restrict__ WT,
    const float* __restrict__ bia, const float* __restrict__ g,
    const float* __restrict__ beta, ushort_t* __restrict__ out) {
  __shared__ short Al[32 * 72];
  __shared__ short Bl[256 * 72];
  __shared__ float red1[32][2], red2[32][2];
  const int t = threadIdx.x;
  const int wv = t >> 6, lane = t & 63, l16 = lane & 15, quad = lane >> 4;
  const int wm = wv >> 1, wn = wv & 1;
  const int row0 = blockIdx.x * 32;

  f4 acc[8];
#pragma unroll
  for (int nf = 0; nf < 8; ++nf) acc[nf] = (f4){0.f, 0.f, 0.f, 0.f};

  for (int k0 = 0; k0 < 512; k0 += 64) {
    __syncthreads();
    {   // stage A: 32 x 64, fp32 -> bf16 (one uint4 per thread)
      const int r = t >> 3, c8 = t & 7;
      const float* src = &A[(size_t)(row0 + r) * 512 + k0 + c8 * 8];
      *(uint4*)&Al[r * 72 + c8 * 8] =
          pack8(*(const float4*)src, *(const float4*)(src + 4));
    }
#pragma unroll
    for (int i = 0; i < 8; ++i) {       // stage B: 256 x 64
      const int ch = t + i * 256;
      const int r = ch >> 3, c8 = ch & 7;
      *(uint4*)&Bl[r * 72 + c8 * 8] =
          *(const uint4*)&WT[(size_t)r * 512 + k0 + c8 * 8];
    }
    __syncthreads();
#pragma unroll
    for (int kc = 0; kc < 2; ++kc) {
      const s8 af = *(const s8*)&Al[(wm * 16 + l16) * 72 + kc * 32 + quad * 8];
#pragma unroll
      for (int nf = 0; nf < 8; ++nf) {
        const s8 bf = *(const s8*)&Bl[(wn * 128 + nf * 16 + l16) * 72 + kc * 32 + quad * 8];
        acc[nf] = __builtin_amdgcn_mfma_f32_16x16x32_bf16(af, bf, acc[nf], 0, 0, 0);
      }
    }
  }
  float bi[8], gg[8], bb[8];
#pragma unroll
  for (int nf = 0; nf < 8; ++nf) {
    const int col = wn * 128 + nf * 16 + l16;
    bi[nf] = bia[col]; gg[nf] = g[col]; bb[nf] = beta[col];
  }
  float s1[4] = {0.f, 0.f, 0.f, 0.f}, s2[4] = {0.f, 0.f, 0.f, 0.f};
#pragma unroll
  for (int nf = 0; nf < 8; ++nf)
#pragma unroll
    for (int r = 0; r < 4; ++r) {
      const float v = acc[nf][r] + bi[nf];
      acc[nf][r] = v;
      s1[r] += v; s2[r] += v * v;
    }
#pragma unroll
  for (int m = 1; m < 16; m <<= 1) {
#pragma unroll
    for (int r = 0; r < 4; ++r) {
      s1[r] += __shfl_xor(s1[r], m);
      s2[r] += __shfl_xor(s2[r], m);
    }
  }
  if (l16 == 0) {
#pragma unroll
    for (int r = 0; r < 4; ++r) {
      const int rl = wm * 16 + quad * 4 + r;
      red1[rl][wn] = s1[r]; red2[rl][wn] = s2[r];
    }
  }
  __syncthreads();
#pragma unroll
  for (int r = 0; r < 4; ++r) {
    const int rl = wm * 16 + quad * 4 + r;
    const float mu = (red1[rl][0] + red1[rl][1]) * (1.f / 256.f);
    const float var = (red2[rl][0] + red2[rl][1]) * (1.f / 256.f) - mu * mu;
    const float rstd = rsqrtf(var + 1e-5f);
#pragma unroll
    for (int nf = 0; nf < 8; ++nf) {
      const int col = wn * 128 + nf * 16 + l16;
      const float v = (acc[nf][r] - mu) * rstd * gg[nf] + bb[nf];
      out[(size_t)(row0 + rl) * 256 + col] = f2bf(fmaxf(v, 0.f));
    }
  }
}

// ---- QKV GEMM: A=h_bf, WT=wqkvT [768][256]; q scaled 1/16, v -> VT ----
__global__ __launch_bounds__(256, 4) void k_gemm_qkv(
    const ushort_t* __restrict__ A, const ushort_t* __restrict__ WT,
    const float* __restrict__ bq, const float* __restrict__ bk,
    const float* __restrict__ bv,
    ushort_t* __restrict__ q, ushort_t* __restrict__ k, ushort_t* __restrict__ vt) {
  __shared__ short Al[64 * 72];
  __shared__ short Bl[128 * 72];
  const int t = threadIdx.x;
  const int wv = t >> 6, lane = t & 63, l16 = lane & 15, quad = lane >> 4;
  const int wm = wv >> 1, wn = wv & 1;
  const int row0 = blockIdx.x * 64;
  const int nb = blockIdx.y;
  const int type = nb >> 1;
  const ushort_t* wtb = WT + (size_t)nb * 128 * 256;

  f4 acc[2][4];
#pragma unroll
  for (int mf = 0; mf < 2; ++mf)
#pragma unroll
    for (int nf = 0; nf < 4; ++nf) acc[mf][nf] = (f4){0.f, 0.f, 0.f, 0.f};

  for (int k0 = 0; k0 < 256; k0 += 64) {
    __syncthreads();
#pragma unroll
    for (int i = 0; i < 2; ++i) {
      const int ch = t + i * 256;
      const int r = ch >> 3, c8 = ch & 7;
      *(uint4*)&Al[r * 72 + c8 * 8] =
          *(const uint4*)&A[(size_t)(row0 + r) * 256 + k0 + c8 * 8];
    }
#pragma unroll
    for (int i = 0; i < 4; ++i) {
      const int ch = t + i * 256;
      const int r = ch >> 3, c8 = ch & 7;
      *(uint4*)&Bl[r * 72 + c8 * 8] =
          *(const uint4*)&wtb[(size_t)r * 256 + k0 + c8 * 8];
    }
    __syncthreads();
#pragma unroll
    for (int kc = 0; kc < 2; ++kc) {
      s8 af[2];
      af[0] = *(const s8*)&Al[(wm * 32 + l16) * 72 + kc * 32 + quad * 8];
      af[1] = *(const s8*)&Al[(wm * 32 + 16 + l16) * 72 + kc * 32 + quad * 8];
#pragma unroll
      for (int nf = 0; nf < 4; ++nf) {
        const s8 bf = *(const s8*)&Bl[(wn * 64 + nf * 16 + l16) * 72 + kc * 32 + quad * 8];
        acc[0][nf] = __builtin_amdgcn_mfma_f32_16x16x32_bf16(af[0], bf, acc[0][nf], 0, 0, 0);
        acc[1][nf] = __builtin_amdgcn_mfma_f32_16x16x32_bf16(af[1], bf, acc[1][nf], 0, 0, 0);
      }
    }
  }
  const float* bias = (type == 0) ? bq : (type == 1) ? bk : bv;
#pragma unroll
  for (int nf = 0; nf < 4; ++nf) {
    const int colg = nb * 128 + wn * 64 + nf * 16 + l16;
    const int col = colg - type * 256;
    const float bi = bias[col];
    if (type == 2) {
      const int b = row0 >> 11;
#pragma unroll
      for (int mf = 0; mf < 2; ++mf) {
        const int n = (row0 & 2047) + wm * 32 + mf * 16 + quad * 4;
        ushort4 pk;
        pk.x = f2bf(acc[mf][nf][0] + bi);
        pk.y = f2bf(acc[mf][nf][1] + bi);
        pk.z = f2bf(acc[mf][nf][2] + bi);
        pk.w = f2bf(acc[mf][nf][3] + bi);
        *(ushort4*)&vt[((size_t)b * 256 + col) * 2048 + n] = pk;
      }
    } else {
      ushort_t* dst = (type == 0) ? q : k;
      const float sc = (type == 0) ? 0.0625f : 1.f;
#pragma unroll
      for (int mf = 0; mf < 2; ++mf)
#pragma unroll
        for (int r = 0; r < 4; ++r) {
          const int row = row0 + wm * 32 + mf * 16 + quad * 4 + r;
          dst[(size_t)row * 256 + col] = f2bf((acc[mf][nf][r] + bi) * sc);
        }
    }
  }
}

// ---- MFMA flash attention v3: R4 LDS staging + correctly-placed reg prefetch ----
// grid (32 qtiles, 2 ks, 8 batch), 256 thr = 4 waves x 16 q; LDS 80 KB -> 2 blocks/CU
// prefetch for tile t+1 issued AFTER the post-commit barrier, so the loads fly
// across the whole compute phase and the next barrier's vmcnt(0) drain is free.
#define KLS 264
#define VTS 72
#define PLS 72
__global__ __launch_bounds__(256, 2) void k_attn(
    const ushort_t* __restrict__ qb, const ushort_t* __restrict__ kb,
    const ushort_t* __restrict__ vtb,
    const float* __restrict__ coords, const int* __restrict__ mask,
    const float* __restrict__ gam,
    float* __restrict__ Op, float* __restrict__ mws, float* __restrict__ lws) {
  __shared__ short klds[64 * KLS];   // 33792 B
  __shared__ short vtl[256 * VTS];   // 36864 B
  __shared__ short pl[64 * PLS];     //  9216 B
  const int t = threadIdx.x;
  const int wv = t >> 6, lane = t & 63, l16 = lane & 15, quad = lane >> 4;
  const int b = blockIdx.z, ks = blockIdx.y;
  const int qw = blockIdx.x * 64 + wv * 16;
  const int kbase = ks * 1024;

  // Q A-frags resident in regs for all 16 tiles
  s8 qa[8];
  {
    const ushort_t* qrow = qb + ((size_t)b * 2048 + qw + l16) * 256;
#pragma unroll
    for (int c = 0; c < 8; ++c)
      qa[c] = *(const s8*)(qrow + c * 32 + quad * 8);
  }
  float rcx[4], rcy[4];
#pragma unroll
  for (int r = 0; r < 4; ++r) {
    const float2 cc = ((const float2*)coords)[b * 2048 + qw + quad * 4 + r];
    rcx[r] = cc.x; rcy[r] = cc.y;
  }
  const float gamma = fabsf(gam[0]);

  f4 o[16];
#pragma unroll
  for (int i = 0; i < 16; ++i) o[i] = (f4){0.f, 0.f, 0.f, 0.f};
  float mrun[4] = {-1e30f, -1e30f, -1e30f, -1e30f};
  float lrun[4] = {0.f, 0.f, 0.f, 0.f};

  const ushort_t* kbb = kb + ((size_t)b * 2048 + kbase) * 256;
  const ushort_t* vbb = vtb + (size_t)b * 256 * 2048 + kbase;

  // prefetch tile 0 into registers
  uint4 kpre[8], vpre[8];
#pragma unroll
  for (int i = 0; i < 8; ++i) {
    const int ch = t + i * 256;
    kpre[i] = *(const uint4*)(kbb + (size_t)(ch >> 5) * 256 + (ch & 31) * 8);
    vpre[i] = *(const uint4*)(vbb + (size_t)(ch >> 3) * 2048 + (ch & 7) * 8);
  }

  for (int kt = 0; kt < 16; ++kt) {
    const int m0 = kbase + kt * 64;
    __syncthreads();                    // prev tile LDS reads done; aged prefetch drains free
#pragma unroll
    for (int i = 0; i < 8; ++i) {       // commit prefetched tile to LDS
      const int ch = t + i * 256;
      *(uint4*)&klds[(ch >> 5) * KLS + (ch & 31) * 8] = kpre[i];
      *(uint4*)&vtl[(ch >> 3) * VTS + (ch & 7) * 8] = vpre[i];
    }
    __syncthreads();                    // LDS ready (nothing in flight -> cheap drain)
    if (kt + 1 < 16) {                  // issue next-tile loads: fly across compute phase
      const ushort_t* kn = kbb + (size_t)(kt + 1) * 64 * 256;
      const ushort_t* vn = vbb + (kt + 1) * 64;
#pragma unroll
      for (int i = 0; i < 8; ++i) {
        const int ch = t + i * 256;
        kpre[i] = *(const uint4*)(kn + (size_t)(ch >> 5) * 256 + (ch & 31) * 8);
        vpre[i] = *(const uint4*)(vn + (size_t)(ch >> 3) * 2048 + (ch & 7) * 8);
      }
    }
    // QK^T
    f4 sc[4];
#pragma unroll
    for (int s = 0; s < 4; ++s) sc[s] = (f4){0.f, 0.f, 0.f, 0.f};
#pragma unroll
    for (int s = 0; s < 4; ++s) {
      const short* kr = &klds[(s * 16 + l16) * KLS + quad * 8];
#pragma unroll
      for (int c = 0; c < 8; ++c) {
        const s8 bf = *(const s8*)(kr + c * 32);
        sc[s] = __builtin_amdgcn_mfma_f32_16x16x32_bf16(qa[c], bf, sc[s], 0, 0, 0);
      }
    }
    // online softmax on raw scores
    float mt[4];
#pragma unroll
    for (int r = 0; r < 4; ++r)
      mt[r] = fmaxf(fmaxf(sc[0][r], sc[1][r]), fmaxf(sc[2][r], sc[3][r]));
#pragma unroll
    for (int o2 = 1; o2 < 16; o2 <<= 1) {
#pragma unroll
      for (int r = 0; r < 4; ++r) mt[r] = fmaxf(mt[r], __shfl_xor(mt[r], o2));
    }
    float alpha[4];
#pragma unroll
    for (int r = 0; r < 4; ++r) {
      const float mn = fmaxf(mrun[r], mt[r]);
      alpha[r] = __expf(mrun[r] - mn);
      mrun[r] = mn;
    }
    float p[4][4], ls[4] = {0.f, 0.f, 0.f, 0.f};
#pragma unroll
    for (int s = 0; s < 4; ++s) {
#pragma unroll
      for (int r = 0; r < 4; ++r) { p[s][r] = __expf(sc[s][r] - mrun[r]); ls[r] += p[s][r]; }
    }
#pragma unroll
    for (int o2 = 1; o2 < 16; o2 <<= 1) {
#pragma unroll
      for (int r = 0; r < 4; ++r) ls[r] += __shfl_xor(ls[r], o2);
    }
#pragma unroll
    for (int r = 0; r < 4; ++r) lrun[r] = lrun[r] * alpha[r] + ls[r];
    // weights = p * exp(-gamma*dist) * maskf -> per-wave pl band (A-layout roundtrip)
#pragma unroll
    for (int s = 0; s < 4; ++s) {
      const int m = m0 + s * 16 + l16;
      const float2 cc = ((const float2*)coords)[b * 2048 + m];
      const float mf = mask[b * 2048 + m] ? 0.f : 1.f;
#pragma unroll
      for (int r = 0; r < 4; ++r) {
        const float dx = rcx[r] - cc.x, dy = rcy[r] - cc.y;
        const float dist = sqrtf(fmaxf(dx * dx + dy * dy, 0.f));
        const float w = p[s][r] * __expf(-gamma * dist) * mf;
        pl[(wv * 16 + quad * 4 + r) * PLS + s * 16 + l16] = (short)f2bf(w);
      }
    }
#pragma unroll
    for (int i = 0; i < 16; ++i) {
#pragma unroll
      for (int r = 0; r < 4; ++r) o[i][r] *= alpha[r];
    }
    const s8 pa0 = *(const s8*)&pl[(wv * 16 + l16) * PLS + quad * 8];
    const s8 pa1 = *(const s8*)&pl[(wv * 16 + l16) * PLS + 32 + quad * 8];
    // PV from LDS V^T
#pragma unroll
    for (int ds2 = 0; ds2 < 16; ++ds2) {
      const short* vr = &vtl[(ds2 * 16 + l16) * VTS + quad * 8];
      const s8 b0 = *(const s8*)vr;
      const s8 b1 = *(const s8*)(vr + 32);
      o[ds2] = __builtin_amdgcn_mfma_f32_16x16x32_bf16(pa0, b0, o[ds2], 0, 0, 0);
      o[ds2] = __builtin_amdgcn_mfma_f32_16x16x32_bf16(pa1, b1, o[ds2], 0, 0, 0);
    }
  }
  float* OpK = Op + (size_t)ks * 4194304;
#pragma unroll
  for (int r = 0; r < 4; ++r) {
    float* orow = OpK + ((size_t)b * 2048 + qw + quad * 4 + r) * 256 + l16;
#pragma unroll
    for (int ds2 = 0; ds2 < 16; ++ds2) orow[ds2 * 16] = o[ds2][r];
  }
  if (l16 == 0) {
#pragma unroll
    for (int r = 0; r < 4; ++r) {
      mws[ks * 16384 + b * 2048 + qw + quad * 4 + r] = mrun[r];
      lws[ks * 16384 + b * 2048 + qw + quad * 4 + r] = lrun[r];
    }
  }
}

// ---- BN GEMM + LN + ReLU, 32-row blocks (grid 512), fused 2-way softmax merge ----
__global__ __launch_bounds__(256, 3) void k_gemm_bn(
    const float* __restrict__ Op, const float* __restrict__ mws,
    const float* __restrict__ lws, const ushort_t* __restrict__ WT,
    const float* __restrict__ bia, const float* __restrict__ g,
    const float* __restrict__ beta, ushort_t* __restrict__ out) {
  __shared__ short Al[32 * 72];
  __shared__ short Bl[128 * 72];
  __shared__ float red1[32][2], red2[32][2];
  __shared__ float sC[32][2];
  const int t = threadIdx.x;
  const int wv = t >> 6, lane = t & 63, l16 = lane & 15, quad = lane >> 4;
  const int wm = wv >> 1, wn = wv & 1;
  const int row0 = blockIdx.x * 32;

  if (t < 32) {
    const int row = row0 + t;
    const float m0 = mws[row], m1 = mws[16384 + row];
    const float l0 = lws[row], l1 = lws[16384 + row];
    const float M = fmaxf(m0, m1);
    const float a0 = __expf(m0 - M), a1 = __expf(m1 - M);
    const float rd = 1.f / (l0 * a0 + l1 * a1);
    sC[t][0] = a0 * rd; sC[t][1] = a1 * rd;
  }

  f4 acc[4];
#pragma unroll
  for (int nf = 0; nf < 4; ++nf) acc[nf] = (f4){0.f, 0.f, 0.f, 0.f};

  for (int k0 = 0; k0 < 256; k0 += 64) {
    __syncthreads();
    {   // stage A: merge 2 partials -> bf16 (one uint4 per thread)
      const int r = t >> 3, c8 = t & 7;
      const float c0 = sC[r][0], c1 = sC[r][1];
      const size_t off = (size_t)(row0 + r) * 256 + k0 + c8 * 8;
      const float4 xa0 = *(const float4*)&Op[off];
      const float4 xb0 = *(const float4*)&Op[off + 4];
      const float4 xa1 = *(const float4*)&Op[4194304 + off];
      const float4 xb1 = *(const float4*)&Op[4194304 + off + 4];
      float4 ea, eb;
      ea.x = c0 * xa0.x + c1 * xa1.x; ea.y = c0 * xa0.y + c1 * xa1.y;
      ea.z = c0 * xa0.z + c1 * xa1.z; ea.w = c0 * xa0.w + c1 * xa1.w;
      eb.x = c0 * xb0.x + c1 * xb1.x; eb.y = c0 * xb0.y + c1 * xb1.y;
      eb.z = c0 * xb0.z + c1 * xb1.z; eb.w = c0 * xb0.w + c1 * xb1.w;
      *(uint4*)&Al[r * 72 + c8 * 8] = pack8(ea, eb);
    }
#pragma unroll
    for (int i = 0; i < 4; ++i) {
      const int ch = t + i * 256;
      const int r = ch >> 3, c8 = ch & 7;
      *(uint4*)&Bl[r * 72 + c8 * 8] =
          *(const uint4*)&WT[(size_t)r * 256 + k0 + c8 * 8];
    }
    __syncthreads();
#pragma unroll
    for (int kc = 0; kc < 2; ++kc) {
      const s8 af = *(const s8*)&Al[(wm * 16 + l16) * 72 + kc * 32 + quad * 8];
#pragma unroll
      for (int nf = 0; nf < 4; ++nf) {
        const s8 bf = *(const s8*)&Bl[(wn * 64 + nf * 16 + l16) * 72 + kc * 32 + quad * 8];
        acc[nf] = __builtin_amdgcn_mfma_f32_16x16x32_bf16(af, bf, acc[nf], 0, 0, 0);
      }
    }
  }
  float bi[4], gg[4], bb[4];
#pragma unroll
  for (int nf = 0; nf < 4; ++nf) {
    const int col = wn * 64 + nf * 16 + l16;
    bi[nf] = bia[col]; gg[nf] = g[col]; bb[nf] = beta[col];
  }
  float s1[4] = {0.f, 0.f, 0.f, 0.f}, s2[4] = {0.f, 0.f, 0.f, 0.f};
#pragma unroll
  for (int nf = 0; nf < 4; ++nf)
#pragma unroll
    for (int r = 0; r < 4; ++r) {
      const float v = acc[nf][r] + bi[nf];
      acc[nf][r] = v;
      s1[r] += v; s2[r] += v * v;
    }
#pragma unroll
  for (int m = 1; m < 16; m <<= 1) {
#pragma unroll
    for (int r = 0; r < 4; ++r) {
      s1[r] += __shfl_xor(s1[r], m);
      s2[r] += __shfl_xor(s2[r], m);
    }
  }
  if (l16 == 0) {
#pragma unroll
    for (int r = 0; r < 4; ++r) {
      const int rl = wm * 16 + quad * 4 + r;
      red1[rl][wn] = s1[r]; red2[rl][wn] = s2[r];
    }
  }
  __syncthreads();
#pragma unroll
  for (int r = 0; r < 4; ++r) {
    const int rl = wm * 16 + quad * 4 + r;
    const float mu = (red1[rl][0] + red1[rl][1]) * (1.f / 128.f);
    const float var = (red2[rl][0] + red2[rl][1]) * (1.f / 128.f) - mu * mu;
    const float rstd = rsqrtf(var + 1e-5f);
#pragma unroll
    for (int nf = 0; nf < 4; ++nf) {
      const int col = wn * 64 + nf * 16 + l16;
      const float v = (acc[nf][r] - mu) * rstd * gg[nf] + bb[nf];
      out[(size_t)(row0 + rl) * 128 + col] = f2bf(fmaxf(v, 0.f));
    }
  }
}

// ---------------- masked mean pool stage 1 ----------------
__global__ __launch_bounds__(128) void k_pool1(
    const ushort_t* __restrict__ obn, const int* __restrict__ mask,
    float* __restrict__ pp) {
  const int g = blockIdx.x, b = blockIdx.y, d = threadIdx.x;
  const ushort_t* ob = obn + ((size_t)b * 2048 + g * 128) * 128;
  const int* mb = mask + b * 2048 + g * 128;
  float s = 0.f, cnt = 0.f;
  for (int n = 0; n < 128; ++n) {
    const float w = mb[n] ? 0.f : 1.f;
    s += w * bf2f(ob[(size_t)n * 128 + d]);
    cnt += w;
  }
  pp[(b * 16 + g) * 132 + d] = s;
  if (d == 0) pp[(b * 16 + g) * 132 + 128] = cnt;
}

// ---------------- fused pool stage 2 + MLP head ----------------
__global__ __launch_bounds__(128) void k_pool2_head(
    const float* __restrict__ pp, const float* __restrict__ c1w,
    const float* __restrict__ c1b, const float* __restrict__ c2w,
    const float* __restrict__ c2b, float* __restrict__ dout) {
  __shared__ float ps[128];
  __shared__ float h1[64];
  const int b = blockIdx.x, t = threadIdx.x;
  float s = 0.f, cnt = 0.f;
  for (int g = 0; g < 16; ++g) {
    s += pp[(b * 16 + g) * 132 + t];
    cnt += pp[(b * 16 + g) * 132 + 128];
  }
  const float p = s / fmaxf(cnt, 1e-9f);
  ps[t] = p;
  dout[80 + b * 128 + t] = p;
  __syncthreads();
  if (t < 64) {
    float acc = c1b[t];
    for (int d = 0; d < 128; ++d) acc += ps[d] * c1w[d * 64 + t];
    h1[t] = fmaxf(acc, 0.f);
  }
  __syncthreads();
  if (t < 10) {
    float a2 = c2b[t];
    for (int j = 0; j < 64; ++j) a2 += h1[j] * c2w[j * 10 + t];
    dout[b * 10 + t] = a2;
  }
}

extern "C" void kernel_launch(void* const* d_in, const int* in_sizes, int n_in,
                              void* d_out, int out_size, void* d_ws, size_t ws_size,
                              hipStream_t stream) {
  const float* lf     = (const float*)d_in[0];
  const float* coords = (const float*)d_in[1];
  const int*   mask   = (const int*)d_in[2];
  const float* enc_w  = (const float*)d_in[3];
  const float* enc_b  = (const float*)d_in[4];
  const float* enc_g  = (const float*)d_in[5];
  const float* enc_be = (const float*)d_in[6];
  const float* gamma  = (const float*)d_in[7];
  const float* wq     = (const float*)d_in[8];
  const float* bq     = (const float*)d_in[9];
  const float* wk     = (const float*)d_in[10];
  const float* bk     = (const float*)d_in[11];
  const float* wv     = (const float*)d_in[12];
  const float* bv     = (const float*)d_in[13];
  const float* bn_w   = (const float*)d_in[14];
  const float* bn_b   = (const float*)d_in[15];
  const float* bn_g   = (const float*)d_in[16];
  const float* bn_be  = (const float*)d_in[17];
  const float* c1w    = (const float*)d_in[18];
  const float* c1b    = (const float*)d_in[19];
  const float* c2w    = (const float*)d_in[20];
  const float* c2b    = (const float*)d_in[21];

  // ws layout (float units), ~68 MB:
  //  [0,2M) h_bf | [2M,4M) q_bf | [4M,6M) k_bf | [6M,8M) vt_bf
  //  [8M,16M) Op[2] fp32 partials (obn_bf aliases Op0 after attention)
  //  [16M,...) enc_wT | wqkvT | bn_wT | mws | lws | ppart
  float* ws = (float*)d_ws;
  ushort_t* h_bf   = (ushort_t*)ws;
  ushort_t* q_bf   = (ushort_t*)(ws + 2097152);
  ushort_t* k_bf   = (ushort_t*)(ws + 4194304);
  ushort_t* vt_bf  = (ushort_t*)(ws + 6291456);
  float*    Op     = ws + 8388608;                 // 2 x 4194304 floats
  ushort_t* obn_bf = (ushort_t*)(ws + 8388608);    // aliases Op0 after k_attn
  ushort_t* enc_wT = (ushort_t*)(ws + 16777216);   // [256][512]
  ushort_t* wqkvT  = (ushort_t*)(ws + 16842752);   // [768][256]
  ushort_t* bn_wT  = (ushort_t*)(ws + 16941056);   // [128][256]
  float*    mws    = ws + 16957440;                // 2 x 16384
  float*    lws    = ws + 16990208;                // 2 x 16384
  float*    ppart  = ws + 17022976;                // 8*16*132
  float* out = (float*)d_out;

  k_wt_all<<<dim3(512, 5), 256, 0, stream>>>(enc_w, wq, wk, wv, bn_w,
                                             enc_wT, wqkvT, bn_wT);
  k_gemm_enc<<<512, 256, 0, stream>>>(lf, enc_wT, enc_b, enc_g, enc_be, h_bf);
  k_gemm_qkv<<<dim3(256, 6), 256, 0, stream>>>(h_bf, wqkvT, bq, bk, bv, q_bf, k_bf, vt_bf);
  k_attn<<<dim3(32, 2, 8), 256, 0, stream>>>(q_bf, k_bf, vt_bf, coords, mask, gamma,
                                             Op, mws, lws);
  k_gemm_bn<<<512, 256, 0, stream>>>(Op, mws, lws, bn_wT, bn_b, bn_g, bn_be, obn_bf);
  k_pool1<<<dim3(16, 8), 128, 0, stream>>>(obn_bf, mask, ppart);
  k_pool2_head<<<8, 128, 0, stream>>>(ppart, c1w, c1b, c2w, c2b, out);
}

// Round 7
// 269.336 us; speedup vs baseline: 1.4910x; 1.3476x over previous
//
#include <hip/hip_runtime.h>
#include <hip/hip_bf16.h>

typedef unsigned short ushort_t;
typedef __attribute__((ext_vector_type(8))) short s8;    // 8 bf16 (4 VGPRs)
typedef __attribute__((ext_vector_type(4))) float f4;    // MFMA C/D frag

__device__ __forceinline__ unsigned short f2bf(float f) {
  union { float f; unsigned int u; } c; c.f = f;
  unsigned int r = (c.u + 0x7fffu + ((c.u >> 16) & 1u)) >> 16;
  return (unsigned short)r;
}
__device__ __forceinline__ float bf2f(ushort_t u) {
  union { unsigned int i; float f; } c; c.i = ((unsigned int)u) << 16; return c.f;
}
__device__ __forceinline__ uint4 pack8(float4 a, float4 b) {
  uint4 r;
  r.x = (unsigned)f2bf(a.x) | ((unsigned)f2bf(a.y) << 16);
  r.y = (unsigned)f2bf(a.z) | ((unsigned)f2bf(a.w) << 16);
  r.z = (unsigned)f2bf(b.x) | ((unsigned)f2bf(b.y) << 16);
  r.w = (unsigned)f2bf(b.z) | ((unsigned)f2bf(b.w) << 16);
  return r;
}
// global -> LDS DMA, 16B per lane, wave-uniform LDS base + lane*16
__device__ __forceinline__ void dma16(const ushort_t* g, const short* l) {
  __builtin_amdgcn_global_load_lds(
      (const __attribute__((address_space(1))) unsigned int*)g,
      (__attribute__((address_space(3))) unsigned int*)(unsigned long)l,
      16, 0, 0);
}

// ---------- all weight transposes in one launch: dst[n][k] = bf16(src[k][n]) ----------
__global__ __launch_bounds__(256) void k_wt_all(
    const float* __restrict__ enc_w, const float* __restrict__ wq,
    const float* __restrict__ wk, const float* __restrict__ wv,
    const float* __restrict__ bn_w,
    ushort_t* __restrict__ enc_wT, ushort_t* __restrict__ wqkvT,
    ushort_t* __restrict__ bn_wT) {
  const int y = blockIdx.y;
  const int i = blockIdx.x * 256 + threadIdx.x;
  if (y == 0) {
    if (i < 131072) { const int n = i >> 9, k = i & 511; enc_wT[i] = f2bf(enc_w[k * 256 + n]); }
  } else if (y <= 3) {
    if (i < 65536) {
      const int n = i >> 8, k = i & 255;
      const float* src = (y == 1) ? wq : (y == 2) ? wk : wv;
      wqkvT[(y - 1) * 65536 + i] = f2bf(src[k * 256 + n]);
    }
  } else {
    if (i < 32768) { const int n = i >> 8, k = i & 255; bn_wT[i] = f2bf(bn_w[k * 128 + n]); }
  }
}

// ------- encoder GEMM + LN + ReLU; 32-row blocks (grid 512), A fp32->bf16 in staging -------
__global__ __launch_bounds__(256, 3) void k_gemm_enc(
    const float* __restrict__ A, const ushort_t* __restrict__ WT,
    const float* __restrict__ bia, const float* __restrict__ g,
    const float* __restrict__ beta, ushort_t* __restrict__ out) {
  __shared__ short Al[32 * 72];
  __shared__ short Bl[256 * 72];
  __shared__ float red1[32][2], red2[32][2];
  const int t = threadIdx.x;
  const int wv = t >> 6, lane = t & 63, l16 = lane & 15, quad = lane >> 4;
  const int wm = wv >> 1, wn = wv & 1;
  const int row0 = blockIdx.x * 32;

  f4 acc[8];
#pragma unroll
  for (int nf = 0; nf < 8; ++nf) acc[nf] = (f4){0.f, 0.f, 0.f, 0.f};

  for (int k0 = 0; k0 < 512; k0 += 64) {
    __syncthreads();
    {
      const int r = t >> 3, c8 = t & 7;
      const float* src = &A[(size_t)(row0 + r) * 512 + k0 + c8 * 8];
      *(uint4*)&Al[r * 72 + c8 * 8] =
          pack8(*(const float4*)src, *(const float4*)(src + 4));
    }
#pragma unroll
    for (int i = 0; i < 8; ++i) {
      const int ch = t + i * 256;
      const int r = ch >> 3, c8 = ch & 7;
      *(uint4*)&Bl[r * 72 + c8 * 8] =
          *(const uint4*)&WT[(size_t)r * 512 + k0 + c8 * 8];
    }
    __syncthreads();
#pragma unroll
    for (int kc = 0; kc < 2; ++kc) {
      const s8 af = *(const s8*)&Al[(wm * 16 + l16) * 72 + kc * 32 + quad * 8];
#pragma unroll
      for (int nf = 0; nf < 8; ++nf) {
        const s8 bf = *(const s8*)&Bl[(wn * 128 + nf * 16 + l16) * 72 + kc * 32 + quad * 8];
        acc[nf] = __builtin_amdgcn_mfma_f32_16x16x32_bf16(af, bf, acc[nf], 0, 0, 0);
      }
    }
  }
  float bi[8], gg[8], bb[8];
#pragma unroll
  for (int nf = 0; nf < 8; ++nf) {
    const int col = wn * 128 + nf * 16 + l16;
    bi[nf] = bia[col]; gg[nf] = g[col]; bb[nf] = beta[col];
  }
  float s1[4] = {0.f, 0.f, 0.f, 0.f}, s2[4] = {0.f, 0.f, 0.f, 0.f};
#pragma unroll
  for (int nf = 0; nf < 8; ++nf)
#pragma unroll
    for (int r = 0; r < 4; ++r) {
      const float v = acc[nf][r] + bi[nf];
      acc[nf][r] = v;
      s1[r] += v; s2[r] += v * v;
    }
#pragma unroll
  for (int m = 1; m < 16; m <<= 1) {
#pragma unroll
    for (int r = 0; r < 4; ++r) {
      s1[r] += __shfl_xor(s1[r], m);
      s2[r] += __shfl_xor(s2[r], m);
    }
  }
  if (l16 == 0) {
#pragma unroll
    for (int r = 0; r < 4; ++r) {
      const int rl = wm * 16 + quad * 4 + r;
      red1[rl][wn] = s1[r]; red2[rl][wn] = s2[r];
    }
  }
  __syncthreads();
#pragma unroll
  for (int r = 0; r < 4; ++r) {
    const int rl = wm * 16 + quad * 4 + r;
    const float mu = (red1[rl][0] + red1[rl][1]) * (1.f / 256.f);
    const float var = (red2[rl][0] + red2[rl][1]) * (1.f / 256.f) - mu * mu;
    const float rstd = rsqrtf(var + 1e-5f);
#pragma unroll
    for (int nf = 0; nf < 8; ++nf) {
      const int col = wn * 128 + nf * 16 + l16;
      const float v = (acc[nf][r] - mu) * rstd * gg[nf] + bb[nf];
      out[(size_t)(row0 + rl) * 256 + col] = f2bf(fmaxf(v, 0.f));
    }
  }
}

// ---- QKV GEMM: A=h_bf, WT=wqkvT [768][256]; q scaled 1/16, v -> VT ----
__global__ __launch_bounds__(256, 4) void k_gemm_qkv(
    const ushort_t* __restrict__ A, const ushort_t* __restrict__ WT,
    const float* __restrict__ bq, const float* __restrict__ bk,
    const float* __restrict__ bv,
    ushort_t* __restrict__ q, ushort_t* __restrict__ k, ushort_t* __restrict__ vt) {
  __shared__ short Al[64 * 72];
  __shared__ short Bl[128 * 72];
  const int t = threadIdx.x;
  const int wv = t >> 6, lane = t & 63, l16 = lane & 15, quad = lane >> 4;
  const int wm = wv >> 1, wn = wv & 1;
  const int row0 = blockIdx.x * 64;
  const int nb = blockIdx.y;
  const int type = nb >> 1;
  const ushort_t* wtb = WT + (size_t)nb * 128 * 256;

  f4 acc[2][4];
#pragma unroll
  for (int mf = 0; mf < 2; ++mf)
#pragma unroll
    for (int nf = 0; nf < 4; ++nf) acc[mf][nf] = (f4){0.f, 0.f, 0.f, 0.f};

  for (int k0 = 0; k0 < 256; k0 += 64) {
    __syncthreads();
#pragma unroll
    for (int i = 0; i < 2; ++i) {
      const int ch = t + i * 256;
      const int r = ch >> 3, c8 = ch & 7;
      *(uint4*)&Al[r * 72 + c8 * 8] =
          *(const uint4*)&A[(size_t)(row0 + r) * 256 + k0 + c8 * 8];
    }
#pragma unroll
    for (int i = 0; i < 4; ++i) {
      const int ch = t + i * 256;
      const int r = ch >> 3, c8 = ch & 7;
      *(uint4*)&Bl[r * 72 + c8 * 8] =
          *(const uint4*)&wtb[(size_t)r * 256 + k0 + c8 * 8];
    }
    __syncthreads();
#pragma unroll
    for (int kc = 0; kc < 2; ++kc) {
      s8 af[2];
      af[0] = *(const s8*)&Al[(wm * 32 + l16) * 72 + kc * 32 + quad * 8];
      af[1] = *(const s8*)&Al[(wm * 32 + 16 + l16) * 72 + kc * 32 + quad * 8];
#pragma unroll
      for (int nf = 0; nf < 4; ++nf) {
        const s8 bf = *(const s8*)&Bl[(wn * 64 + nf * 16 + l16) * 72 + kc * 32 + quad * 8];
        acc[0][nf] = __builtin_amdgcn_mfma_f32_16x16x32_bf16(af[0], bf, acc[0][nf], 0, 0, 0);
        acc[1][nf] = __builtin_amdgcn_mfma_f32_16x16x32_bf16(af[1], bf, acc[1][nf], 0, 0, 0);
      }
    }
  }
  const float* bias = (type == 0) ? bq : (type == 1) ? bk : bv;
#pragma unroll
  for (int nf = 0; nf < 4; ++nf) {
    const int colg = nb * 128 + wn * 64 + nf * 16 + l16;
    const int col = colg - type * 256;
    const float bi = bias[col];
    if (type == 2) {
      const int b = row0 >> 11;
#pragma unroll
      for (int mf = 0; mf < 2; ++mf) {
        const int n = (row0 & 2047) + wm * 32 + mf * 16 + quad * 4;
        ushort4 pk;
        pk.x = f2bf(acc[mf][nf][0] + bi);
        pk.y = f2bf(acc[mf][nf][1] + bi);
        pk.z = f2bf(acc[mf][nf][2] + bi);
        pk.w = f2bf(acc[mf][nf][3] + bi);
        *(ushort4*)&vt[((size_t)b * 256 + col) * 2048 + n] = pk;
      }
    } else {
      ushort_t* dst = (type == 0) ? q : k;
      const float sc = (type == 0) ? 0.0625f : 1.f;
#pragma unroll
      for (int mf = 0; mf < 2; ++mf)
#pragma unroll
        for (int r = 0; r < 4; ++r) {
          const int row = row0 + wm * 32 + mf * 16 + quad * 4 + r;
          dst[(size_t)row * 256 + col] = f2bf((acc[mf][nf][r] + bi) * sc);
        }
    }
  }
}

// ---- MFMA flash attention v5: LDS double-buffer via global_load_lds DMA ----
// grid (32 qtiles, 2 ks, 8 batch), 256 thr = 4 waves x 16 q
// KT=32 keys/tile, 32 tiles; LDS 69 KB -> 2 blocks/CU; ONE barrier per tile.
// K LDS layout: [d-chunk c:32][m:32] x 8 shorts (DMA-contiguous, 2-way-bank reads)
// V LDS layout: [m-chunk q:4][d:256] x 8 shorts (same properties)
__global__ __launch_bounds__(256, 2) void k_attn(
    const ushort_t* __restrict__ qb, const ushort_t* __restrict__ kb,
    const ushort_t* __restrict__ vtb,
    const float* __restrict__ coords, const int* __restrict__ mask,
    const float* __restrict__ gam,
    float* __restrict__ Op, float* __restrict__ mws, float* __restrict__ lws) {
  __shared__ short kld[2][8192];   // 2 x 16 KB
  __shared__ short vld[2][8192];   // 2 x 16 KB
  __shared__ short pl[64 * 40];    // 5 KB (padded; ds-written, not DMA)
  const int t = threadIdx.x;
  const int wv = t >> 6, lane = t & 63, l16 = lane & 15, quad = lane >> 4;
  const int b = blockIdx.z, ks = blockIdx.y;
  const int qw = blockIdx.x * 64 + wv * 16;
  const int kbase = ks * 1024;

  // Q A-frags resident (q pre-scaled by 1/16)
  s8 qa[8];
  {
    const ushort_t* qrow = qb + ((size_t)b * 2048 + qw + l16) * 256;
#pragma unroll
    for (int c = 0; c < 8; ++c)
      qa[c] = *(const s8*)(qrow + c * 32 + quad * 8);
  }
  float rcx[4], rcy[4];
#pragma unroll
  for (int r = 0; r < 4; ++r) {
    const float2 cc = ((const float2*)coords)[b * 2048 + qw + quad * 4 + r];
    rcx[r] = cc.x; rcy[r] = cc.y;
  }
  const float gamma = fabsf(gam[0]);

  f4 o[16];
#pragma unroll
  for (int i = 0; i < 16; ++i) o[i] = (f4){0.f, 0.f, 0.f, 0.f};
  float mrun[4] = {-1e30f, -1e30f, -1e30f, -1e30f};
  float lrun[4] = {0.f, 0.f, 0.f, 0.f};

  const ushort_t* kbb = kb + ((size_t)b * 2048 + kbase) * 256;
  const ushort_t* vbb = vtb + (size_t)b * 256 * 2048 + kbase;

  // stage tile 0 into buffer 0 (4 K-DMA + 4 V-DMA per wave)
#pragma unroll
  for (int i = 0; i < 4; ++i) {
    const int i2 = wv * 4 + i;           // K instr: chunks i2*2, i2*2+1
    dma16(kbb + (size_t)(lane & 31) * 256 + (i2 * 2 + (lane >> 5)) * 8,
          &kld[0][i2 * 512]);
    dma16(vbb + (size_t)(i * 64 + lane) * 2048 + wv * 8,   // V instr: q=wv, dblk=i
          &vld[0][(wv * 256 + i * 64) * 8]);
  }
  __syncthreads();

  for (int kt = 0; kt < 32; ++kt) {
    const int cur = kt & 1;
    const int m0 = kbase + kt * 32;
    if (kt < 31) {                       // DMA next tile into idle buffer
      const ushort_t* kn = kbb + (size_t)(kt + 1) * 32 * 256;
      const ushort_t* vn = vbb + (kt + 1) * 32;
      const int nb2 = cur ^ 1;
#pragma unroll
      for (int i = 0; i < 4; ++i) {
        const int i2 = wv * 4 + i;
        dma16(kn + (size_t)(lane & 31) * 256 + (i2 * 2 + (lane >> 5)) * 8,
              &kld[nb2][i2 * 512]);
        dma16(vn + (size_t)(i * 64 + lane) * 2048 + wv * 8,
              &vld[nb2][(wv * 256 + i * 64) * 8]);
      }
    }
    // QK^T: S[16 x 32] per wave
    f4 sc[2];
    sc[0] = (f4){0.f, 0.f, 0.f, 0.f};
    sc[1] = (f4){0.f, 0.f, 0.f, 0.f};
#pragma unroll
    for (int s = 0; s < 2; ++s) {
#pragma unroll
      for (int c = 0; c < 8; ++c) {
        const s8 bf = *(const s8*)&kld[cur][((c * 4 + quad) * 32 + s * 16 + l16) * 8];
        sc[s] = __builtin_amdgcn_mfma_f32_16x16x32_bf16(qa[c], bf, sc[s], 0, 0, 0);
      }
    }
    // online softmax on raw scores
    float mt[4];
#pragma unroll
    for (int r = 0; r < 4; ++r) mt[r] = fmaxf(sc[0][r], sc[1][r]);
#pragma unroll
    for (int o2 = 1; o2 < 16; o2 <<= 1) {
#pragma unroll
      for (int r = 0; r < 4; ++r) mt[r] = fmaxf(mt[r], __shfl_xor(mt[r], o2));
    }
    float alpha[4];
#pragma unroll
    for (int r = 0; r < 4; ++r) {
      const float mn = fmaxf(mrun[r], mt[r]);
      alpha[r] = __expf(mrun[r] - mn);
      mrun[r] = mn;
    }
    float p[2][4], ls[4] = {0.f, 0.f, 0.f, 0.f};
#pragma unroll
    for (int s = 0; s < 2; ++s) {
#pragma unroll
      for (int r = 0; r < 4; ++r) { p[s][r] = __expf(sc[s][r] - mrun[r]); ls[r] += p[s][r]; }
    }
#pragma unroll
    for (int o2 = 1; o2 < 16; o2 <<= 1) {
#pragma unroll
      for (int r = 0; r < 4; ++r) ls[r] += __shfl_xor(ls[r], o2);
    }
#pragma unroll
    for (int r = 0; r < 4; ++r) lrun[r] = lrun[r] * alpha[r] + ls[r];
    // weights -> pl (A-layout roundtrip, per-wave band)
#pragma unroll
    for (int s = 0; s < 2; ++s) {
      const int m = m0 + s * 16 + l16;
      const float2 cc = ((const float2*)coords)[b * 2048 + m];
      const float mf = mask[b * 2048 + m] ? 0.f : 1.f;
#pragma unroll
      for (int r = 0; r < 4; ++r) {
        const float dx = rcx[r] - cc.x, dy = rcy[r] - cc.y;
        const float dist = sqrtf(fmaxf(dx * dx + dy * dy, 0.f));
        const float w = p[s][r] * __expf(-gamma * dist) * mf;
        pl[(wv * 16 + quad * 4 + r) * 40 + s * 16 + l16] = (short)f2bf(w);
      }
    }
#pragma unroll
    for (int i = 0; i < 16; ++i) {
#pragma unroll
      for (int r = 0; r < 4; ++r) o[i][r] *= alpha[r];
    }
    const s8 pa = *(const s8*)&pl[(wv * 16 + l16) * 40 + quad * 8];
    // PV: O[16 x 256] += P[16 x 32] * V[32 x 256]
#pragma unroll
    for (int ds2 = 0; ds2 < 16; ++ds2) {
      const s8 bv = *(const s8*)&vld[cur][(quad * 256 + ds2 * 16 + l16) * 8];
      o[ds2] = __builtin_amdgcn_mfma_f32_16x16x32_bf16(pa, bv, o[ds2], 0, 0, 0);
    }
    __syncthreads();   // drains: LDS reads done + next-tile DMA (aged) complete
  }
  // write partial O and stats
  float* OpK = Op + (size_t)ks * 4194304;
#pragma unroll
  for (int r = 0; r < 4; ++r) {
    float* orow = OpK + ((size_t)b * 2048 + qw + quad * 4 + r) * 256 + l16;
#pragma unroll
    for (int ds2 = 0; ds2 < 16; ++ds2) orow[ds2 * 16] = o[ds2][r];
  }
  if (l16 == 0) {
#pragma unroll
    for (int r = 0; r < 4; ++r) {
      mws[ks * 16384 + b * 2048 + qw + quad * 4 + r] = mrun[r];
      lws[ks * 16384 + b * 2048 + qw + quad * 4 + r] = lrun[r];
    }
  }
}

// ---- BN GEMM + LN + ReLU, 32-row blocks (grid 512), fused 2-way softmax merge ----
__global__ __launch_bounds__(256, 3) void k_gemm_bn(
    const float* __restrict__ Op, const float* __restrict__ mws,
    const float* __restrict__ lws, const ushort_t* __restrict__ WT,
    const float* __restrict__ bia, const float* __restrict__ g,
    const float* __restrict__ beta, ushort_t* __restrict__ out) {
  __shared__ short Al[32 * 72];
  __shared__ short Bl[128 * 72];
  __shared__ float red1[32][2], red2[32][2];
  __shared__ float sC[32][2];
  const int t = threadIdx.x;
  const int wv = t >> 6, lane = t & 63, l16 = lane & 15, quad = lane >> 4;
  const int wm = wv >> 1, wn = wv & 1;
  const int row0 = blockIdx.x * 32;

  if (t < 32) {
    const int row = row0 + t;
    const float m0 = mws[row], m1 = mws[16384 + row];
    const float l0 = lws[row], l1 = lws[16384 + row];
    const float M = fmaxf(m0, m1);
    const float a0 = __expf(m0 - M), a1 = __expf(m1 - M);
    const float rd = 1.f / (l0 * a0 + l1 * a1);
    sC[t][0] = a0 * rd; sC[t][1] = a1 * rd;
  }

  f4 acc[4];
#pragma unroll
  for (int nf = 0; nf < 4; ++nf) acc[nf] = (f4){0.f, 0.f, 0.f, 0.f};

  for (int k0 = 0; k0 < 256; k0 += 64) {
    __syncthreads();
    {
      const int r = t >> 3, c8 = t & 7;
      const float c0 = sC[r][0], c1 = sC[r][1];
      const size_t off = (size_t)(row0 + r) * 256 + k0 + c8 * 8;
      const float4 xa0 = *(const float4*)&Op[off];
      const float4 xb0 = *(const float4*)&Op[off + 4];
      const float4 xa1 = *(const float4*)&Op[4194304 + off];
      const float4 xb1 = *(const float4*)&Op[4194304 + off + 4];
      float4 ea, eb;
      ea.x = c0 * xa0.x + c1 * xa1.x; ea.y = c0 * xa0.y + c1 * xa1.y;
      ea.z = c0 * xa0.z + c1 * xa1.z; ea.w = c0 * xa0.w + c1 * xa1.w;
      eb.x = c0 * xb0.x + c1 * xb1.x; eb.y = c0 * xb0.y + c1 * xb1.y;
      eb.z = c0 * xb0.z + c1 * xb1.z; eb.w = c0 * xb0.w + c1 * xb1.w;
      *(uint4*)&Al[r * 72 + c8 * 8] = pack8(ea, eb);
    }
#pragma unroll
    for (int i = 0; i < 4; ++i) {
      const int ch = t + i * 256;
      const int r = ch >> 3, c8 = ch & 7;
      *(uint4*)&Bl[r * 72 + c8 * 8] =
          *(const uint4*)&WT[(size_t)r * 256 + k0 + c8 * 8];
    }
    __syncthreads();
#pragma unroll
    for (int kc = 0; kc < 2; ++kc) {
      const s8 af = *(const s8*)&Al[(wm * 16 + l16) * 72 + kc * 32 + quad * 8];
#pragma unroll
      for (int nf = 0; nf < 4; ++nf) {
        const s8 bf = *(const s8*)&Bl[(wn * 64 + nf * 16 + l16) * 72 + kc * 32 + quad * 8];
        acc[nf] = __builtin_amdgcn_mfma_f32_16x16x32_bf16(af, bf, acc[nf], 0, 0, 0);
      }
    }
  }
  float bi[4], gg[4], bb[4];
#pragma unroll
  for (int nf = 0; nf < 4; ++nf) {
    const int col = wn * 64 + nf * 16 + l16;
    bi[nf] = bia[col]; gg[nf] = g[col]; bb[nf] = beta[col];
  }
  float s1[4] = {0.f, 0.f, 0.f, 0.f}, s2[4] = {0.f, 0.f, 0.f, 0.f};
#pragma unroll
  for (int nf = 0; nf < 4; ++nf)
#pragma unroll
    for (int r = 0; r < 4; ++r) {
      const float v = acc[nf][r] + bi[nf];
      acc[nf][r] = v;
      s1[r] += v; s2[r] += v * v;
    }
#pragma unroll
  for (int m = 1; m < 16; m <<= 1) {
#pragma unroll
    for (int r = 0; r < 4; ++r) {
      s1[r] += __shfl_xor(s1[r], m);
      s2[r] += __shfl_xor(s2[r], m);
    }
  }
  if (l16 == 0) {
#pragma unroll
    for (int r = 0; r < 4; ++r) {
      const int rl = wm * 16 + quad * 4 + r;
      red1[rl][wn] = s1[r]; red2[rl][wn] = s2[r];
    }
  }
  __syncthreads();
#pragma unroll
  for (int r = 0; r < 4; ++r) {
    const int rl = wm * 16 + quad * 4 + r;
    const float mu = (red1[rl][0] + red1[rl][1]) * (1.f / 128.f);
    const float var = (red2[rl][0] + red2[rl][1]) * (1.f / 128.f) - mu * mu;
    const float rstd = rsqrtf(var + 1e-5f);
#pragma unroll
    for (int nf = 0; nf < 4; ++nf) {
      const int col = wn * 64 + nf * 16 + l16;
      const float v = (acc[nf][r] - mu) * rstd * gg[nf] + bb[nf];
      out[(size_t)(row0 + rl) * 128 + col] = f2bf(fmaxf(v, 0.f));
    }
  }
}

// ---------------- masked mean pool stage 1 ----------------
__global__ __launch_bounds__(128) void k_pool1(
    const ushort_t* __restrict__ obn, const int* __restrict__ mask,
    float* __restrict__ pp) {
  const int g = blockIdx.x, b = blockIdx.y, d = threadIdx.x;
  const ushort_t* ob = obn + ((size_t)b * 2048 + g * 128) * 128;
  const int* mb = mask + b * 2048 + g * 128;
  float s = 0.f, cnt = 0.f;
  for (int n = 0; n < 128; ++n) {
    const float w = mb[n] ? 0.f : 1.f;
    s += w * bf2f(ob[(size_t)n * 128 + d]);
    cnt += w;
  }
  pp[(b * 16 + g) * 132 + d] = s;
  if (d == 0) pp[(b * 16 + g) * 132 + 128] = cnt;
}

// ---------------- fused pool stage 2 + MLP head ----------------
__global__ __launch_bounds__(128) void k_pool2_head(
    const float* __restrict__ pp, const float* __restrict__ c1w,
    const float* __restrict__ c1b, const float* __restrict__ c2w,
    const float* __restrict__ c2b, float* __restrict__ dout) {
  __shared__ float ps[128];
  __shared__ float h1[64];
  const int b = blockIdx.x, t = threadIdx.x;
  float s = 0.f, cnt = 0.f;
  for (int g = 0; g < 16; ++g) {
    s += pp[(b * 16 + g) * 132 + t];
    cnt += pp[(b * 16 + g) * 132 + 128];
  }
  const float p = s / fmaxf(cnt, 1e-9f);
  ps[t] = p;
  dout[80 + b * 128 + t] = p;
  __syncthreads();
  if (t < 64) {
    float acc = c1b[t];
    for (int d = 0; d < 128; ++d) acc += ps[d] * c1w[d * 64 + t];
    h1[t] = fmaxf(acc, 0.f);
  }
  __syncthreads();
  if (t < 10) {
    float a2 = c2b[t];
    for (int j = 0; j < 64; ++j) a2 += h1[j] * c2w[j * 10 + t];
    dout[b * 10 + t] = a2;
  }
}

extern "C" void kernel_launch(void* const* d_in, const int* in_sizes, int n_in,
                              void* d_out, int out_size, void* d_ws, size_t ws_size,
                              hipStream_t stream) {
  const float* lf     = (const float*)d_in[0];
  const float* coords = (const float*)d_in[1];
  const int*   mask   = (const int*)d_in[2];
  const float* enc_w  = (const float*)d_in[3];
  const float* enc_b  = (const float*)d_in[4];
  const float* enc_g  = (const float*)d_in[5];
  const float* enc_be = (const float*)d_in[6];
  const float* gamma  = (const float*)d_in[7];
  const float* wq     = (const float*)d_in[8];
  const float* bq     = (const float*)d_in[9];
  const float* wk     = (const float*)d_in[10];
  const float* bk     = (const float*)d_in[11];
  const float* wv     = (const float*)d_in[12];
  const float* bv     = (const float*)d_in[13];
  const float* bn_w   = (const float*)d_in[14];
  const float* bn_b   = (const float*)d_in[15];
  const float* bn_g   = (const float*)d_in[16];
  const float* bn_be  = (const float*)d_in[17];
  const float* c1w    = (const float*)d_in[18];
  const float* c1b    = (const float*)d_in[19];
  const float* c2w    = (const float*)d_in[20];
  const float* c2b    = (const float*)d_in[21];

  float* ws = (float*)d_ws;
  ushort_t* h_bf   = (ushort_t*)ws;
  ushort_t* q_bf   = (ushort_t*)(ws + 2097152);
  ushort_t* k_bf   = (ushort_t*)(ws + 4194304);
  ushort_t* vt_bf  = (ushort_t*)(ws + 6291456);
  float*    Op     = ws + 8388608;                 // 2 x 4194304 floats
  ushort_t* obn_bf = (ushort_t*)(ws + 8388608);    // aliases Op0 after k_attn
  ushort_t* enc_wT = (ushort_t*)(ws + 16777216);
  ushort_t* wqkvT  = (ushort_t*)(ws + 16842752);
  ushort_t* bn_wT  = (ushort_t*)(ws + 16941056);
  float*    mws    = ws + 16957440;
  float*    lws    = ws + 16990208;
  float*    ppart  = ws + 17022976;
  float* out = (float*)d_out;

  k_wt_all<<<dim3(512, 5), 256, 0, stream>>>(enc_w, wq, wk, wv, bn_w,
                                             enc_wT, wqkvT, bn_wT);
  k_gemm_enc<<<512, 256, 0, stream>>>(lf, enc_wT, enc_b, enc_g, enc_be, h_bf);
  k_gemm_qkv<<<dim3(256, 6), 256, 0, stream>>>(h_bf, wqkvT, bq, bk, bv, q_bf, k_bf, vt_bf);
  k_attn<<<dim3(32, 2, 8), 256, 0, stream>>>(q_bf, k_bf, vt_bf, coords, mask, gamma,
                                             Op, mws, lws);
  k_gemm_bn<<<512, 256, 0, stream>>>(Op, mws, lws, bn_wT, bn_b, bn_g, bn_be, obn_bf);
  k_pool1<<<dim3(16, 8), 128, 0, stream>>>(obn_bf, mask, ppart);
  k_pool2_head<<<8, 128, 0, stream>>>(ppart, c1w, c1b, c2w, c2b, out);
}